// Round 6
// baseline (140.992 us; speedup 1.0000x reference)
//
#include <hip/hip_runtime.h>
#include <math.h>

#define N       8192
#define BLK     256
#define JCHUNK  256                  // B-points per block (one slice)
#define NSLICE  (N / JCHUNK)         // 32
#define ITILES  (N / BLK)            // 32
#define HALF    (ITILES * NSLICE)    // 1024 blocks per direction
#define GRID    (2 * HALF)           // 2048 = 8 blocks/CU, 32 waves/CU (max TLP)

// ---------------------------------------------------- precompute + init ----
// P[0..N) = target packed {x,y,z,|p|^2}; P[N..2N) = output packed.
// dmin[0..2N) = +inf bits; cnt = 0.
__global__ __launch_bounds__(BLK) void chamfer_prep_kernel(
        const float* __restrict__ tgt, const float* __restrict__ outp,
        float4* __restrict__ P, unsigned* __restrict__ dmin,
        unsigned* __restrict__ cnt) {
    int i = blockIdx.x * BLK + (int)threadIdx.x;   // 0 .. 2N-1
    if (i == 0) cnt[0] = 0u;
    const float* src = (i < N) ? tgt : outp;
    int k = (i < N) ? i : (i - N);
    float x = src[3 * k + 0];
    float y = src[3 * k + 1];
    float z = src[3 * k + 2];
    P[i] = make_float4(x, y, z, fmaf(x, x, fmaf(y, y, z * z)));
    dmin[i] = 0x7F800000u;  // +inf
}

// ---------------------------------------------------------------- dist ----
// R2 geometry (proven fastest: full occupancy, 512K total atomics) with the
// j-loop unrolled 16x so the compiler can hoist the wave-uniform scalar
// loads far ahead of their uses instead of stalling per 4-point group.
// d^2 = |a|^2 + (|b|^2 - 2 a.b); |a|^2 commutes with min. 4 ops/pair.
__global__ __launch_bounds__(BLK, 8) void chamfer_dist_kernel(
        const float4* __restrict__ P, unsigned* __restrict__ dmin,
        unsigned* __restrict__ cnt,
        const int* __restrict__ curp, const int* __restrict__ subp,
        float* __restrict__ out) {
    __shared__ int   lastf;
    __shared__ float red1[BLK / 64], red2[BLK / 64];

    int tid = (int)threadIdx.x;
    int bid = (int)blockIdx.x;
    int dir = (bid >= HALF) ? 1 : 0;
    if (dir) bid -= HALF;
    int aoff = dir ? N : 0;
    int boff = dir ? 0 : N;

    int itile = bid / NSLICE;
    int slice = bid % NSLICE;
    int i = itile * BLK + tid;

    float4 a = P[aoff + i];
    float axm = -2.0f * a.x;
    float aym = -2.0f * a.y;
    float azm = -2.0f * a.z;

    const float inf = __builtin_inff();
    float m0 = inf, m1 = inf, m2 = inf, m3 = inf;

    const float4* __restrict__ bp = P + boff + slice * JCHUNK;  // wave-uniform
    #pragma unroll 16
    for (int j = 0; j < JCHUNK; j += 4) {
        float4 b0 = bp[j + 0];
        float4 b1 = bp[j + 1];
        float4 b2 = bp[j + 2];
        float4 b3 = bp[j + 3];
        m0 = fminf(m0, fmaf(axm, b0.x, fmaf(aym, b0.y, fmaf(azm, b0.z, b0.w))));
        m1 = fminf(m1, fmaf(axm, b1.x, fmaf(aym, b1.y, fmaf(azm, b1.z, b1.w))));
        m2 = fminf(m2, fmaf(axm, b2.x, fmaf(aym, b2.y, fmaf(azm, b2.z, b2.w))));
        m3 = fminf(m3, fmaf(axm, b3.x, fmaf(aym, b3.y, fmaf(azm, b3.z, b3.w))));
    }
    float m = fminf(fminf(m0, m1), fminf(m2, m3));
    float d2 = fmaxf(a.w + m, 0.0f);
    atomicMin(&dmin[aoff + i], __float_as_uint(d2));   // coalesced, 1/thread

    // ---- last block to finish: fused sqrt-mean reduction ----
    __threadfence();
    if (tid == 0) lastf = (atomicAdd(cnt, 1u) == (unsigned)(gridDim.x - 1));
    __syncthreads();
    if (!lastf) return;

    int wid = tid >> 6, lane = tid & 63;
    float s1 = 0.0f, s2 = 0.0f;
    #pragma unroll 4
    for (int t = tid; t < N; t += BLK) {
        unsigned u1 = __hip_atomic_load(&dmin[t],     __ATOMIC_RELAXED, __HIP_MEMORY_SCOPE_AGENT);
        unsigned u2 = __hip_atomic_load(&dmin[N + t], __ATOMIC_RELAXED, __HIP_MEMORY_SCOPE_AGENT);
        s1 += sqrtf(__uint_as_float(u1));
        s2 += sqrtf(__uint_as_float(u2));
    }
    #pragma unroll
    for (int off = 32; off > 0; off >>= 1) {
        s1 += __shfl_down(s1, off, 64);
        s2 += __shfl_down(s2, off, 64);
    }
    if (lane == 0) { red1[wid] = s1; red2[wid] = s2; }
    __syncthreads();
    if (tid == 0) {
        float t1 = 0.0f, t2 = 0.0f;
        #pragma unroll
        for (int w = 0; w < BLK / 64; ++w) { t1 += red1[w]; t2 += red2[w]; }
        int e = curp[0] / subp[0];
        double scale = 10.0 / pow(0.99, (double)e);
        out[0] = (float)((((double)t1 + (double)t2) / (double)N) * 0.5 * scale);
    }
}

// ---------------------------------------------------------------- launch ----
extern "C" void kernel_launch(void* const* d_in, const int* in_sizes, int n_in,
                              void* d_out, int out_size, void* d_ws, size_t ws_size,
                              hipStream_t stream) {
    const float* target = (const float*)d_in[0];   // (1, 8192, 3) f32
    const float* output = (const float*)d_in[1];   // (1, 8192, 3) f32
    const int*   curp   = (const int*)d_in[2];
    const int*   subp   = (const int*)d_in[3];
    float* out = (float*)d_out;

    // ws: float4 P[2N] (256 KB) | uint dmin[2N] (64 KB) | uint cnt
    float4*   P    = (float4*)d_ws;
    unsigned* dmin = (unsigned*)(P + 2 * N);
    unsigned* cnt  = dmin + 2 * N;

    chamfer_prep_kernel<<<2 * N / BLK, BLK, 0, stream>>>(target, output, P, dmin, cnt);
    chamfer_dist_kernel<<<GRID, BLK, 0, stream>>>(P, dmin, cnt, curp, subp, out);
}